// Round 5
// baseline (222.205 us; speedup 1.0000x reference)
//
#include <hip/hip_runtime.h>
#include <hip/hip_bf16.h>
#include <stdint.h>

#define BATCH 4
#define CH 64
#define HW 80
#define NPIX 6400
#define SPLITS 5

typedef __attribute__((ext_vector_type(8))) short bf16x8;
typedef __attribute__((ext_vector_type(4))) float f32x4;

#define QSCALE 1.2011224087864498f   // sqrt(log2(e))
#define ESHIFT 115.41560327111707f   // 80 * log2(e)

static __device__ __forceinline__ unsigned short f2bf(float f) {
  union { float f; unsigned int u; } v; v.f = f;
  unsigned int u = v.u;
  return (unsigned short)((u + 0x7fffu + ((u >> 16) & 1u)) >> 16);
}
static __device__ __forceinline__ float bf2f(unsigned short h) {
  union { unsigned int u; float f; } v; v.u = ((unsigned int)h) << 16;
  return v.f;
}
// two floats -> packed bf16x2 via v_cvt_pk_bf16_f32 (RNE)
static __device__ __forceinline__ unsigned int packrn(float a, float b) {
  __hip_bfloat162 h = __float22bfloat162_rn(make_float2(a, b));
  union { __hip_bfloat162 h; unsigned int u; } v; v.h = h;
  return v.u;
}
// fp32 -> (hi bf16 | lo bf16 << 16)
static __device__ __forceinline__ unsigned int split_pack(float a) {
  unsigned short hi = f2bf(a);
  union { unsigned int u; float f; } hf; hf.u = ((unsigned int)hi) << 16;
  unsigned short lo = f2bf(a - hf.f);
  return (unsigned int)hi | ((unsigned int)lo << 16);
}

// ---------------- QKV 1x1 conv ----------------
__global__ __launch_bounds__(256) void qkv_kernel(
    const float* __restrict__ x, const float* __restrict__ w,
    const float* __restrict__ bias, unsigned short* __restrict__ Qtbf,
    unsigned short* __restrict__ Vbf, unsigned int* __restrict__ Kpk,
    unsigned int* __restrict__ Qpk) {
  __shared__ float qs[64][65];
  int bid = blockIdx.x;
  int b = bid / 100, tile = bid % 100;
  int p0 = tile * 64;
  int t = threadIdx.x;
  int i = t & 63;
  int og = __builtin_amdgcn_readfirstlane(t >> 6);
  int p = p0 + i;
  const float* xb = x + (size_t)b * CH * NPIX + p;
  float xv[64];
#pragma unroll
  for (int c = 0; c < 64; ++c) xv[c] = xb[(size_t)c * NPIX];
  size_t bc = (size_t)b * CH * NPIX;
  for (int j = 0; j < 48; ++j) {
    int o = og * 48 + j;
    const float* wr = w + o * 64;
    float a = bias[o];
#pragma unroll
    for (int c = 0; c < 64; ++c) a += wr[c] * xv[c];
    int cc = o & 63;
    int kind = o >> 6;
    if (kind == 0) {
      qs[cc][i] = a;
      Qpk[bc + (size_t)cc * NPIX + p] = split_pack(a);
    } else if (kind == 1) {
      Kpk[bc + (size_t)cc * NPIX + p] = split_pack(a);
    } else {
      Vbf[bc + (size_t)cc * NPIX + p] = f2bf(a);
    }
  }
  __syncthreads();
  // restage q -> Qtbf rows (row 128B contiguous, scaled by QSCALE)
  int j = t >> 2, g = t & 3;
  int pj = p0 + j;
  int tpj = (pj % HW) * HW + pj / HW;
  unsigned int pk8[8];
#pragma unroll
  for (int q4 = 0; q4 < 8; ++q4) {
    float a0 = qs[g * 16 + q4 * 2][j] * QSCALE;
    float a1 = qs[g * 16 + q4 * 2 + 1][j] * QSCALE;
    pk8[q4] = (unsigned int)f2bf(a0) | ((unsigned int)f2bf(a1) << 16);
  }
  unsigned short* dst = Qtbf + ((size_t)b * NPIX + tpj) * 64 + g * 16;
  uint4 w0 = {pk8[0], pk8[1], pk8[2], pk8[3]};
  uint4 w1 = {pk8[4], pk8[5], pk8[6], pk8[7]};
  *(uint4*)&dst[0] = w0;
  *(uint4*)&dst[8] = w1;
}

// ---------------- channel gram via split-bf16 MFMA ----------------
__global__ __launch_bounds__(256) void gram_kernel(
    const unsigned int* __restrict__ Kpk, const unsigned int* __restrict__ Qpk,
    float* __restrict__ Pc) {
  __shared__ unsigned short Ah[64 * 72], Al[64 * 72], Bh[64 * 72], Bl[64 * 72];
  int bid = blockIdx.x;
  int b = bid / 100, chunk = bid % 100;
  int n0 = chunk * 64;
  int t = threadIdx.x;
  int w = t >> 6, lane = t & 63;
  int quad = lane >> 4, l16 = lane & 15;
  size_t bc = (size_t)b * CH * NPIX;
  int row = t >> 2, g = t & 3;

  const unsigned int* ks = Kpk + bc + (size_t)row * NPIX + n0 + g * 16;
#pragma unroll
  for (int q4 = 0; q4 < 4; ++q4) {
    uint4 u = *(const uint4*)&ks[q4 * 4];
    uint2 h = {(u.x & 0xffffu) | ((u.y & 0xffffu) << 16),
               (u.z & 0xffffu) | ((u.w & 0xffffu) << 16)};
    uint2 l = {(u.x >> 16) | (u.y & 0xffff0000u),
               (u.z >> 16) | (u.w & 0xffff0000u)};
    *(uint2*)&Ah[row * 72 + g * 16 + q4 * 4] = h;
    *(uint2*)&Al[row * 72 + g * 16 + q4 * 4] = l;
  }
  unsigned int qu[16];
#pragma unroll
  for (int ii = 0; ii < 16; ++ii) {
    int n = n0 + g * 16 + ii;
    int tn = (n % HW) * HW + n / HW;
    qu[ii] = Qpk[bc + (size_t)row * NPIX + tn];
  }
#pragma unroll
  for (int q4 = 0; q4 < 4; ++q4) {
    uint2 h = {(qu[q4 * 4] & 0xffffu) | ((qu[q4 * 4 + 1] & 0xffffu) << 16),
               (qu[q4 * 4 + 2] & 0xffffu) | ((qu[q4 * 4 + 3] & 0xffffu) << 16)};
    uint2 l = {(qu[q4 * 4] >> 16) | (qu[q4 * 4 + 1] & 0xffff0000u),
               (qu[q4 * 4 + 2] >> 16) | (qu[q4 * 4 + 3] & 0xffff0000u)};
    *(uint2*)&Bh[row * 72 + g * 16 + q4 * 4] = h;
    *(uint2*)&Bl[row * 72 + g * 16 + q4 * 4] = l;
  }
  __syncthreads();
  f32x4 acc[4];
#pragma unroll
  for (int ct = 0; ct < 4; ++ct) acc[ct] = (f32x4){0.f, 0.f, 0.f, 0.f};
#pragma unroll
  for (int ks2 = 0; ks2 < 2; ++ks2) {
    bf16x8 ah = *(const bf16x8*)&Ah[(w * 16 + l16) * 72 + ks2 * 32 + quad * 8];
    bf16x8 al = *(const bf16x8*)&Al[(w * 16 + l16) * 72 + ks2 * 32 + quad * 8];
#pragma unroll
    for (int ct = 0; ct < 4; ++ct) {
      bf16x8 bh = *(const bf16x8*)&Bh[(ct * 16 + l16) * 72 + ks2 * 32 + quad * 8];
      bf16x8 bl = *(const bf16x8*)&Bl[(ct * 16 + l16) * 72 + ks2 * 32 + quad * 8];
      acc[ct] = __builtin_amdgcn_mfma_f32_16x16x32_bf16(ah, bh, acc[ct], 0, 0, 0);
      acc[ct] = __builtin_amdgcn_mfma_f32_16x16x32_bf16(ah, bl, acc[ct], 0, 0, 0);
      acc[ct] = __builtin_amdgcn_mfma_f32_16x16x32_bf16(al, bh, acc[ct], 0, 0, 0);
    }
  }
#pragma unroll
  for (int ct = 0; ct < 4; ++ct)
#pragma unroll
    for (int r = 0; r < 4; ++r)
      atomicAdd(&Pc[((size_t)b * 64 + w * 16 + quad * 4 + r) * 64 + ct * 16 + l16],
                acc[ct][r]);
}

// ---------------- channel softmax -> maTg[b][cp][c] = ma[c][cp] ----------------
__global__ __launch_bounds__(64) void maT_kernel(const float* __restrict__ Pc,
                                                 float* __restrict__ maTg) {
  int b = blockIdx.x, c = threadIdx.x;
  const float* row = Pc + ((size_t)b * 64 + c) * 64;
  float v[64];
  float mx = -1e30f;
#pragma unroll
  for (int j = 0; j < 64; ++j) { v[j] = row[j]; mx = fmaxf(mx, v[j]); }
  float s = 0.f;
#pragma unroll
  for (int j = 0; j < 64; ++j) { v[j] = __expf(v[j] - mx); s += v[j]; }
  float inv = 1.f / s;
#pragma unroll
  for (int j = 0; j < 64; ++j) maTg[((size_t)b * 64 + j) * 64 + c] = v[j] * inv;
}

// ---------------- flash spatial attention: barrier-free, direct-global K/V ----
// grid 500 = 4b x 25 qtiles(256 rows) x 5 splits; wave owns 64 query rows.
// K/V fragments load straight from global (L1/L2-hot 16KB tiles); only the
// P C-layout->A-layout transform touches LDS (per-wave private, no syncs).
__global__ __launch_bounds__(256, 2) void flash_kernel(
    const unsigned short* __restrict__ Qtbf, const unsigned short* __restrict__ Vbf,
    unsigned short* __restrict__ Opart, float* __restrict__ Lpart) {
  __shared__ unsigned short Pb[4 * 64 * 64];  // 32 KB, per-wave private slices

  int bid = blockIdx.x;
  int b = bid / 125;
  int rem = bid % 125;
  int qt = rem / 5, split = rem % 5;
  int p0 = qt * 256;
  int t = threadIdx.x;
  int w = t >> 6, lane = t & 63;
  int quad = lane >> 4, l16 = lane & 15;
  int sw = l16 & 7;
  size_t bq = (size_t)b * NPIX;
  size_t bC = (size_t)b * CH * NPIX;

  // Q fragments (B operand), loop-invariant: rows p0 + w*64 + mr*16 + l16
  bf16x8 aq[4][2];
#pragma unroll
  for (int mr = 0; mr < 4; ++mr)
#pragma unroll
    for (int ks = 0; ks < 2; ++ks)
      aq[mr][ks] = *(const bf16x8*)&Qtbf[(bq + p0 + w * 64 + mr * 16 + l16) * 64 +
                                         ks * 32 + quad * 8];

  f32x4 oacc[4][4];
#pragma unroll
  for (int mr = 0; mr < 4; ++mr)
#pragma unroll
    for (int ct = 0; ct < 4; ++ct) oacc[mr][ct] = (f32x4){0.f, 0.f, 0.f, 0.f};
  f32x4 lacc[4];
#pragma unroll
  for (int mr = 0; mr < 4; ++mr) lacc[mr] = (f32x4){0.f, 0.f, 0.f, 0.f};
  bf16x8 ones;
#pragma unroll
  for (int j = 0; j < 8; ++j) ones[j] = (short)0x3F80;

  const unsigned short* Kb = Qtbf + bq * 64;
  const unsigned short* Vb = Vbf + bC;
  unsigned short* Pw = Pb + w * 64 * 64;

  int kt0 = split * 20;
  for (int kt = kt0; kt < kt0 + 20; ++kt) {
    int n0 = kt * 64;
    // ---- S phase: K fragments direct from global
    bf16x8 bk[2][4];
#pragma unroll
    for (int ks = 0; ks < 2; ++ks)
#pragma unroll
      for (int ct = 0; ct < 4; ++ct)
        bk[ks][ct] = *(const bf16x8*)&Kb[(size_t)(n0 + ct * 16 + l16) * 64 +
                                         ks * 32 + quad * 8];
#pragma unroll
    for (int mr = 0; mr < 4; ++mr) {
      f32x4 sc[4];
#pragma unroll
      for (int ct = 0; ct < 4; ++ct) {
        sc[ct] = (f32x4){0.f, 0.f, 0.f, 0.f};
        sc[ct] = __builtin_amdgcn_mfma_f32_16x16x32_bf16(bk[0][ct], aq[mr][0], sc[ct], 0, 0, 0);
        sc[ct] = __builtin_amdgcn_mfma_f32_16x16x32_bf16(bk[1][ct], aq[mr][1], sc[ct], 0, 0, 0);
      }
#pragma unroll
      for (int ct = 0; ct < 4; ++ct) {
        float e0 = __builtin_amdgcn_exp2f(sc[ct][0] - ESHIFT);
        float e1 = __builtin_amdgcn_exp2f(sc[ct][1] - ESHIFT);
        float e2 = __builtin_amdgcn_exp2f(sc[ct][2] - ESHIFT);
        float e3 = __builtin_amdgcn_exp2f(sc[ct][3] - ESHIFT);
        uint2 pk = {packrn(e0, e1), packrn(e2, e3)};
        *(uint2*)&Pw[(mr * 16 + l16) * 64 +
                     (((2 * ct + (quad >> 1)) ^ sw) << 3) + ((quad & 1) << 2)] = pk;
      }
    }
    // ---- PV phase: V fragments direct from global
#pragma unroll
    for (int ks = 0; ks < 2; ++ks) {
      bf16x8 vf[4];
#pragma unroll
      for (int ct = 0; ct < 4; ++ct)
        vf[ct] = *(const bf16x8*)&Vb[(size_t)(ct * 16 + l16) * NPIX + n0 +
                                     ks * 32 + quad * 8];
#pragma unroll
      for (int mr = 0; mr < 4; ++mr) {
        bf16x8 pf = *(const bf16x8*)&Pw[(mr * 16 + l16) * 64 +
                                        (((ks * 4 + quad) ^ sw) << 3)];
        lacc[mr] = __builtin_amdgcn_mfma_f32_16x16x32_bf16(ones, pf, lacc[mr], 0, 0, 0);
#pragma unroll
        for (int ct = 0; ct < 4; ++ct)
          oacc[mr][ct] = __builtin_amdgcn_mfma_f32_16x16x32_bf16(vf[ct], pf, oacc[mr][ct], 0, 0, 0);
      }
    }
  }
  // ---- epilogue: Lpart direct stores; O^T -> LDS bf16 -> coalesced stores
#pragma unroll
  for (int mr = 0; mr < 4; ++mr)
    if (quad == 0)
      Lpart[(size_t)(split * BATCH + b) * NPIX + p0 + w * 64 + mr * 16 + l16] =
          lacc[mr][0];
#pragma unroll
  for (int mr = 0; mr < 4; ++mr)
#pragma unroll
    for (int ct = 0; ct < 4; ++ct)
#pragma unroll
      for (int r = 0; r < 4; ++r)
        Pw[(ct * 16 + quad * 4 + r) * 64 + mr * 16 + l16] = f2bf(oacc[mr][ct][r]);
  unsigned short* Ob = Opart + (size_t)(split * BATCH + b) * CH * NPIX + p0 + w * 64;
  int rr = lane >> 3, cc8 = (lane & 7) * 8;
#pragma unroll
  for (int i = 0; i < 8; ++i) {
    uint4 d = *(const uint4*)&Pw[(i * 8 + rr) * 64 + cc8];
    *(uint4*)&Ob[(size_t)(i * 8 + rr) * NPIX + cc8] = d;
  }
}

// ---------------- finalize: out = chan + (sum_s Opart_s)/(sum_s Lpart_s) ------
__global__ __launch_bounds__(256) void finalize_kernel(
    const float* __restrict__ maTg, const unsigned short* __restrict__ Vbf,
    const unsigned short* __restrict__ Opart, const float* __restrict__ Lpart,
    float* __restrict__ out) {
  int bid = blockIdx.x;
  int b = bid / 100, nt = bid % 100;
  int t = threadIdx.x;
  int lane = t & 63;
  int wv = __builtin_amdgcn_readfirstlane(t >> 6);  // ct group, wave-uniform
  int n = nt * 64 + lane;
  size_t bc = (size_t)b * CH * NPIX;
  const unsigned short* vb = Vbf + bc + n;
  const float* mb = maTg + (size_t)b * 4096 + wv * 16;
  float acc[16];
#pragma unroll
  for (int j = 0; j < 16; ++j) acc[j] = 0.f;
  for (int cp = 0; cp < 64; ++cp) {
    float vv = bf2f(vb[(size_t)cp * NPIX]);
    const float* m = mb + cp * 64;  // wave-uniform -> s_loads
#pragma unroll
    for (int j = 0; j < 16; ++j) acc[j] += m[j] * vv;
  }
  float lsum = 0.f;
#pragma unroll
  for (int s = 0; s < SPLITS; ++s)
    lsum += Lpart[(size_t)(s * BATCH + b) * NPIX + n];
  float inv = 1.f / lsum;
#pragma unroll
  for (int j = 0; j < 16; ++j) {
    size_t co = (size_t)(wv * 16 + j) * NPIX + n;
    float o = 0.f;
#pragma unroll
    for (int s = 0; s < SPLITS; ++s)
      o += bf2f(Opart[(size_t)(s * BATCH + b) * CH * NPIX + co]);
    out[bc + co] = acc[j] + o * inv;
  }
}

extern "C" void kernel_launch(void* const* d_in, const int* in_sizes, int n_in,
                              void* d_out, int out_size, void* d_ws, size_t ws_size,
                              hipStream_t stream) {
  const float* x = (const float*)d_in[0];
  const float* w = (const float*)d_in[1];
  const float* bias = (const float*)d_in[2];
  float* out = (float*)d_out;
  char* ws = (char*)d_ws;
  // layout (bytes):
  unsigned short* Qtbf = (unsigned short*)(ws);           // [0, 3276800)
  unsigned short* Vbf = (unsigned short*)(ws + 3276800);  // [3276800, 6553600)
  unsigned int* Kpk = (unsigned int*)(ws + 6553600);      // dead after gram
  unsigned int* Qpk = (unsigned int*)(ws + 13107200);     // dead after gram
  unsigned short* Opart = (unsigned short*)(ws + 6553600);  // [6553600, 22937600) bf16, 5 splits
  float* Pc = (float*)(ws + 22937600);                    // [22937600, 23003136)
  float* maTg = (float*)(ws + 23003136);                  // [23003136, 23068672)
  float* Lpart = (float*)(ws + 23068672);                 // [23068672, 23580672)

  hipMemsetAsync(Pc, 0, 65536, stream);
  qkv_kernel<<<400, 256, 0, stream>>>(x, w, bias, Qtbf, Vbf, Kpk, Qpk);
  gram_kernel<<<400, 256, 0, stream>>>(Kpk, Qpk, Pc);
  maT_kernel<<<4, 64, 0, stream>>>(Pc, maTg);
  flash_kernel<<<500, 256, 0, stream>>>(Qtbf, Vbf, Opart, Lpart);
  finalize_kernel<<<400, 256, 0, stream>>>(maTg, Vbf, Opart, Lpart, out);
}